// Round 2
// baseline (263.892 us; speedup 1.0000x reference)
//
#include <hip/hip_runtime.h>
#include <math.h>

// Shapes (fixed): q(8,256,128,128) c_t(8,256,512) W_a(512,256) W_p(256,512) V_p(2,256)
#define Bq 8
#define Tt 256
#define Dd 256
#define Hh 128
#define Ww 128
#define Cc 512
#define HW (Hh*Ww)
#define NBT (Bq*Tt)   // 2048 tokens

__device__ __forceinline__ float lane_bcast(float x, int l) {
    return __uint_as_float(__builtin_amdgcn_readlane(__float_as_uint(x), l));
}

// ---------------- Kernel 0: transpose W_p (256x512) -> WpT (512x256) ------
__global__ __launch_bounds__(256) void transpose_wp(
    const float* __restrict__ W_p, float* __restrict__ WpT)
{
    __shared__ float tile[32][33];
    const int bx = blockIdx.x;            // c tile (16)
    const int by = blockIdx.y;            // p tile (8)
    const int lx = threadIdx.x & 31, ly = threadIdx.x >> 5;   // 32 x 8
#pragma unroll
    for (int j = 0; j < 4; j++) {
        int p = by * 32 + ly + j * 8;
        tile[ly + j * 8][lx] = W_p[(size_t)p * Cc + bx * 32 + lx];
    }
    __syncthreads();
#pragma unroll
    for (int j = 0; j < 4; j++) {
        int c = bx * 32 + ly + j * 8;
        WpT[(size_t)c * 256 + by * 32 + lx] = tile[lx][ly + j * 8];
    }
}

// ---------------- Kernel 1: u = c_t@W_a, p_t = 128*sig(V_p tanh(W_p c)) ---
// TOK=8 -> 256 blocks (1/CU, 8 waves). ct chunks in registers, lane->wave
// broadcast via v_readlane (VALU only, no memory-pipe broadcasts).
#define TOK 8
__global__ __launch_bounds__(512) void prep_kernel(
    const float* __restrict__ c_t,   // (NBT, 512)
    const float* __restrict__ W_a,   // (512, 256)  [c][d]
    const float* __restrict__ WpT,   // (512, 256)  [c][p]
    const float* __restrict__ V_p,   // (2, 256)
    float* __restrict__ u_ws,        // (NBT, 256)
    float* __restrict__ p_ws)        // (NBT, 2)
{
    __shared__ float y0s[TOK][256];
    __shared__ float y1s[TOK][256];
    const int tid  = threadIdx.x;
    const int o    = tid & 255;
    const int half = tid >> 8;
    const int ln   = tid & 63;
    const int bt0  = blockIdx.x * TOK;

    const float* Wcol = (half ? WpT : W_a) + o;   // column o, stride 256
    const float* ctb  = c_t + (size_t)bt0 * Cc;

    float acc[TOK];
#pragma unroll
    for (int t = 0; t < TOK; t++) acc[t] = 0.f;

    float ctr[TOK], ctn[TOK];
#pragma unroll
    for (int t = 0; t < TOK; t++) ctr[t] = ctb[t * Cc + ln];

#pragma unroll
    for (int c0 = 0; c0 < Cc; c0 += 64) {
        if (c0 + 64 < Cc) {
#pragma unroll
            for (int t = 0; t < TOK; t++) ctn[t] = ctb[t * Cc + c0 + 64 + ln];
        }
#pragma unroll
        for (int cc8 = 0; cc8 < 64; cc8 += 8) {
            float w[8];
#pragma unroll
            for (int j = 0; j < 8; j++)
                w[j] = Wcol[(size_t)(c0 + cc8 + j) * 256];
#pragma unroll
            for (int j = 0; j < 8; j++) {
#pragma unroll
                for (int t = 0; t < TOK; t++)
                    acc[t] = fmaf(lane_bcast(ctr[t], cc8 + j), w[j], acc[t]);
            }
        }
#pragma unroll
        for (int t = 0; t < TOK; t++) ctr[t] = ctn[t];
    }

    if (half == 0) {
#pragma unroll
        for (int t = 0; t < TOK; t++)
            u_ws[(size_t)(bt0 + t) * Dd + o] = acc[t];
    } else {
        float v0 = V_p[o], v1 = V_p[256 + o];
#pragma unroll
        for (int t = 0; t < TOK; t++) {
            float th = tanhf(acc[t]);
            y0s[t][o] = th * v0;
            y1s[t][o] = th * v1;
        }
    }
    __syncthreads();

    // 8 waves: wave w reduces token w (both outputs).
    const int wv = tid >> 6;
    float s0 = y0s[wv][ln] + y0s[wv][ln + 64] + y0s[wv][ln + 128] + y0s[wv][ln + 192];
    float s1 = y1s[wv][ln] + y1s[wv][ln + 64] + y1s[wv][ln + 128] + y1s[wv][ln + 192];
#pragma unroll
    for (int of = 32; of >= 1; of >>= 1) {
        s0 += __shfl_xor(s0, of);
        s1 += __shfl_xor(s1, of);
    }
    if (ln == 0) {
        p_ws[(size_t)(bt0 + wv) * 2 + 0] = 128.f / (1.f + expf(-s0));
        p_ws[(size_t)(bt0 + wv) * 2 + 1] = 128.f / (1.f + expf(-s1));
    }
}

// ---------------- Kernel 2: gather + fused scores + softmax + output ------
// One block of 512 threads per token: 16 d-groups x 16 channels each.
// Same 55 KB fp16 window LDS -> still 2 blocks/CU, but 16 waves/CU
// (4/SIMD, was 2/SIMD) and a halved dependent-load chain per wave
// (4 pipelined rounds of 4 scattered float4 loads instead of 8).
// Pass 2 is split-k across the two 256-thread halves.
__global__ __launch_bounds__(512, 4) void attn_kernel(
    const float* __restrict__ q,     // (8,256,128,128)
    const float* __restrict__ u_ws,  // (NBT,256)
    const float* __restrict__ p_ws,  // (NBT,2)
    float* __restrict__ out)         // (NBT,256)
{
    __shared__ __align__(16) _Float16 win[Dd][9][12];   // 55296 B
    __shared__ __align__(16) float pacc_s[16][9][12];   // 6912 B (reused by pass-2 combine)
    __shared__ float ascore[9][12];
    __shared__ float u_s[Dd];
    __shared__ float w_s[81];
    __shared__ float a_s[81];
    __shared__ float e_s[81];
    __shared__ float rex_s[9], cex_s[9];
    __shared__ int   rr_s[9], cc_s[9];
    __shared__ float m_sh, inv_sh;

    const int tid = threadIdx.x;
    int bt = blockIdx.x;
    bt = ((bt & 7) << 8) | (bt >> 3);    // batch b -> XCD b (L2 affinity)
    const int b = bt >> 8;

    if (tid < Dd) u_s[tid] = u_ws[(size_t)bt * Dd + tid];

    if (tid < 18) {
        int   i = (tid < 9) ? tid : tid - 9;
        float p = p_ws[(size_t)bt * 2 + ((tid < 9) ? 0 : 1)];
        int base = (int)rintf(p);                 // round-half-even = jnp.round
        int v = base + i - 3;                     // round(p)+off+1, off=i-4
        v = min(max(v, 0), 129) % 129;
        float cl = (float)max(v - 1, 0);
        float z  = (cl - p) * 0.25f;
        float ex = -2.f * z * z;
        if (tid < 9) { rr_s[i] = v; rex_s[i] = ex; }
        else         { cc_s[i] = v; cex_s[i] = ex; }
    }
    __syncthreads();

    // Valid cols form one contiguous run: derive aligned load base (uniform).
    int jc0 = 0, c0 = 1;
#pragma unroll
    for (int j = 8; j >= 0; j--)
        if (cc_s[j] > 0) { jc0 = j; c0 = cc_s[j]; }
    const int cb = min((c0 - 1) & ~3, Ww - 12);   // 12-float window covers run
    const int e0 = (c0 - 1) - cb;

    // ---- pipelined loader + fused partial scores ----
    {
        const int g  = tid >> 5;                  // 0..15
        const int l5 = tid & 31;
        const bool lact = (l5 < 27);
        const int li = lact ? ((l5 * 171) >> 9) : 0;   // l5/3
        const int lv = l5 - li * 3;
        const int vr = lact ? rr_s[li] : 1;
        const int rowoff = (max(vr, 1) - 1) * Ww + cb + 4 * lv;
        const float* qp = q + (size_t)b * Dd * HW + rowoff;

        if (lact) {
            // preload the 16 u values this lane consumes (d = g + 16m)
            float u_r[16];
#pragma unroll
            for (int m = 0; m < 16; m++) u_r[m] = u_s[g + 16 * m];

            float px = 0.f, py = 0.f, pz = 0.f, pw = 0.f;
            float4 xb[2][4];
#pragma unroll
            for (int mm = 0; mm < 4; mm++)
                xb[0][mm] = *(const float4*)(qp + (size_t)(g + 16 * mm) * HW);

            for (int it = 0; it < 4; it++) {
                const int cur = it & 1;
                if (it < 3) {
#pragma unroll
                    for (int mm = 0; mm < 4; mm++)
                        xb[cur ^ 1][mm] = *(const float4*)
                            (qp + (size_t)(g + 16 * (4 * (it + 1) + mm)) * HW);
                }
#pragma unroll
                for (int mm = 0; mm < 4; mm++) {
                    const int m  = 4 * it + mm;
                    const int d0 = g + 16 * m;
                    float4 x = xb[cur][mm];
                    float  u = u_r[m];
                    px = fmaf(x.x, u, px); py = fmaf(x.y, u, py);
                    pz = fmaf(x.z, u, pz); pw = fmaf(x.w, u, pw);
                    union { _Float16 h[4]; uint2 uu; } pk;
                    pk.h[0] = (_Float16)x.x; pk.h[1] = (_Float16)x.y;
                    pk.h[2] = (_Float16)x.z; pk.h[3] = (_Float16)x.w;
                    *(uint2*)&win[d0][li][4 * lv] = pk.uu;
                }
            }
            *(float4*)&pacc_s[g][li][4 * lv] = make_float4(px, py, pz, pw);
        }
    }
    __syncthreads();

    // ---- reduce partial scores over the 16 d-groups ----
    if (tid < 108) {
        const int li  = tid / 12;
        const int pos = tid - li * 12;
        float s = 0.f;
#pragma unroll
        for (int g = 0; g < 16; g++) s += pacc_s[g][li][pos];
        ascore[li][pos] = s;
    }
    __syncthreads();

    float a_val = -INFINITY;
    bool  valid_k = false;
    if (tid < 81) {
        const int ki = (tid * 57) >> 9;           // tid/9
        const int kj = tid - ki * 9;
        valid_k = (rr_s[ki] > 0) && (cc_s[kj] > 0);
        const int pos = min(max(e0 + kj - jc0, 0), 11);
        a_val = valid_k ? ascore[ki][pos] : -INFINITY;
        a_s[tid] = a_val;
    }
    __syncthreads();

    // ---- softmax over 81 (wave-0 butterfly) ----
    if (tid < 64) {
        float m = a_s[tid];
        if (tid + 64 < 81) m = fmaxf(m, a_s[tid + 64]);
        for (int o = 32; o >= 1; o >>= 1) m = fmaxf(m, __shfl_xor(m, o));
        if (tid == 0) m_sh = m;
    }
    __syncthreads();
    {
        float e = 0.f;
        if (tid < 81 && valid_k) e = expf(a_val - m_sh);
        if (tid < 81) e_s[tid] = e;
    }
    __syncthreads();
    if (tid < 64) {
        float sv = e_s[tid] + ((tid + 64 < 81) ? e_s[tid + 64] : 0.f);
        for (int o = 32; o >= 1; o >>= 1) sv += __shfl_xor(sv, o);
        if (tid == 0) inv_sh = 1.f / sv;
    }
    __syncthreads();
    if (tid < 81) {
        int i = (tid * 57) >> 9;
        int j = tid - i * 9;
        float g = expf(rex_s[i] + cex_s[j]);
        w_s[tid] = e_s[tid] * inv_sh * g;
    }
    __syncthreads();

    // ---- pass 2 (split-k): out[d] = sum_k w_k * win[d][k] (LDS only) ----
    // Half h handles k = [h*41, h*41+41/40); combine via reused pacc_s LDS.
    float* pacc2 = &pacc_s[0][0][0];              // pacc_s dead after ascore
    {
        const int h  = tid >> 8;                  // wave-uniform (waves 0-3 / 4-7)
        const int dd = tid & 255;
        int posj[9];
#pragma unroll
        for (int j = 0; j < 9; j++) posj[j] = min(max(e0 + j - jc0, 0), 11);
        const _Float16* wd = &win[dd][0][0];
        float acc = 0.f;
        if (h == 0) {
#pragma unroll
            for (int k = 0; k < 41; k++) {
                const int ki = k / 9, kj = k % 9;     // compile-time
                acc = fmaf(w_s[k], (float)wd[ki * 12 + posj[kj]], acc);
            }
        } else {
#pragma unroll
            for (int k = 41; k < 81; k++) {
                const int ki = k / 9, kj = k % 9;     // compile-time
                acc = fmaf(w_s[k], (float)wd[ki * 12 + posj[kj]], acc);
            }
        }
        pacc2[h * 256 + dd] = acc;
    }
    __syncthreads();
    if (tid < Dd) out[(size_t)bt * Dd + tid] = pacc2[tid] + pacc2[256 + tid];
}

extern "C" void kernel_launch(void* const* d_in, const int* in_sizes, int n_in,
                              void* d_out, int out_size, void* d_ws, size_t ws_size,
                              hipStream_t stream) {
    const float* q   = (const float*)d_in[0];
    const float* c_t = (const float*)d_in[1];
    const float* W_a = (const float*)d_in[2];
    const float* W_p = (const float*)d_in[3];
    const float* V_p = (const float*)d_in[4];
    float* out  = (float*)d_out;
    float* u_ws = (float*)d_ws;                       // 2 MB
    float* p_ws = u_ws + (size_t)NBT * Dd;            // 16 KB
    float* WpT  = p_ws + (size_t)NBT * 2;             // 512 KB

    transpose_wp<<<dim3(16, 8), 256, 0, stream>>>(W_p, WpT);
    prep_kernel<<<NBT / TOK, 512, 0, stream>>>(c_t, W_a, WpT, V_p, u_ws, p_ws);
    attn_kernel<<<NBT, 512, 0, stream>>>(q, u_ws, p_ws, out);
}